// Round 7
// baseline (244.027 us; speedup 1.0000x reference)
//
#include <hip/hip_runtime.h>

typedef __bf16 bf16x8 __attribute__((ext_vector_type(8)));
typedef float  f32x4  __attribute__((ext_vector_type(4)));

#define NBAT 16
#define NP   2048
#define ND   64
#define NOUT 128
#define NK   16
#define RT   8             // rows per knn block (33 KB tile -> 4 blocks/CU)
#define HSTR 2052          // d2 LDS row stride in halves (4104 B, 8B-aligned)
#define WSTR 132           // W LDS stride (floats)
#define XSTR 68            // x tile LDS stride (floats)

static __device__ __forceinline__ unsigned short f2bf(float f) {
    unsigned u = __float_as_uint(f);
    u += 0x7FFF + ((u >> 16) & 1);      // RNE
    return (unsigned short)(u >> 16);
}
static __device__ __forceinline__ int lanes_below(unsigned long long m) {
    return (int)__builtin_amdgcn_mbcnt_hi((unsigned)(m >> 32),
             __builtin_amdgcn_mbcnt_lo((unsigned)m, 0u));
}
static __device__ __forceinline__ unsigned long long umin64(unsigned long long a, unsigned long long b){ return a < b ? a : b; }
static __device__ __forceinline__ unsigned long long umax64(unsigned long long a, unsigned long long b){ return a < b ? b : a; }

// ascending bitonic sort of 64 u64 keys (one per lane)
static __device__ __forceinline__ unsigned long long bitonic_sort64_u64(unsigned long long v, int lane) {
#pragma unroll
    for (int k = 2; k <= 64; k <<= 1) {
#pragma unroll
        for (int j = k >> 1; j >= 1; j >>= 1) {
            unsigned long long o = __shfl_xor(v, j, 64);
            bool up    = ((lane & k) == 0);
            bool lower = ((lane & j) == 0);
            v = (up == lower) ? umin64(v, o) : umax64(v, o);
        }
    }
    return v;
}

// ascending bitonic sort of 128 u64 keys, element e = slot*64 + lane (rare path)
static __device__ __forceinline__ void bitonic_sort128_u64(unsigned long long &k0,
                                                           unsigned long long &k1, int lane) {
#pragma unroll
    for (int k = 2; k <= 64; k <<= 1) {
#pragma unroll
        for (int j = k >> 1; j >= 1; j >>= 1) {
            bool lower = ((lane & j) == 0);
            bool up0 = (k == 64) ? true  : ((lane & k) == 0);
            bool up1 = (k == 64) ? false : ((lane & k) == 0);
            unsigned long long o0 = __shfl_xor(k0, j, 64);
            k0 = (up0 == lower) ? umin64(k0, o0) : umax64(k0, o0);
            unsigned long long o1 = __shfl_xor(k1, j, 64);
            k1 = (up1 == lower) ? umin64(k1, o1) : umax64(k1, o1);
        }
    }
    { unsigned long long mn = umin64(k0, k1), mx = umax64(k0, k1); k0 = mn; k1 = mx; }
#pragma unroll
    for (int j = 32; j >= 1; j >>= 1) {
        bool lower = ((lane & j) == 0);
        unsigned long long o0 = __shfl_xor(k0, j, 64);
        k0 = lower ? umin64(k0, o0) : umax64(k0, o0);
        unsigned long long o1 = __shfl_xor(k1, j, 64);
        k1 = lower ? umin64(k1, o1) : umax64(k1, o1);
    }
}

// fp64-exact squared distance -> sortable key (fp32 bits << 11 | idx)
static __device__ __forceinline__ unsigned long long
refine_key(const float* __restrict__ x, int gr, int gcbase, int jc) {
    if (jc == 0xFFFF) return ~0ull;
    const float* xr = x + (size_t)gr * ND;
    const float* xc = x + (size_t)(gcbase + jc) * ND;
    double s0 = 0.0, s1 = 0.0;
#pragma unroll
    for (int k8 = 0; k8 < 8; ++k8) {
        float4 a = *(const float4*)(xr + k8 * 8);
        float4 b = *(const float4*)(xc + k8 * 8);
        float4 a2 = *(const float4*)(xr + k8 * 8 + 4);
        float4 b2 = *(const float4*)(xc + k8 * 8 + 4);
        double e0 = (double)a.x - (double)b.x;
        double e1 = (double)a.y - (double)b.y;
        double e2 = (double)a.z - (double)b.z;
        double e3 = (double)a.w - (double)b.w;
        s0 = fma(e0, e0, s0); s0 = fma(e1, e1, s0);
        s0 = fma(e2, e2, s0); s0 = fma(e3, e3, s0);
        double f0 = (double)a2.x - (double)b2.x;
        double f1 = (double)a2.y - (double)b2.y;
        double f2 = (double)a2.z - (double)b2.z;
        double f3 = (double)a2.w - (double)b2.w;
        s1 = fma(f0, f0, s1); s1 = fma(f1, f1, s1);
        s1 = fma(f2, f2, s1); s1 = fma(f3, f3, s1);
    }
    float d = (float)(s0 + s1);
    return (((unsigned long long)__float_as_uint(d)) << 11) | (unsigned)jc;
}

// ---------------------------------------------------------------------------
// prep: sq (fp64-acc), xb16 (bf16 copy of x), U=(W1-W2)x+b, V=W2x  (fp32)
// grid 2048 x 256 (16 rows/block)
// ---------------------------------------------------------------------------
__global__ void __launch_bounds__(256, 1)
prep_k(const float* __restrict__ x,     // [32768][64]
       const float* __restrict__ W,     // [128][128]  (cols 0..63 = W1, 64..127 = W2)
       const float* __restrict__ bias,  // [128]
       float* __restrict__ sq, float* __restrict__ U,
       float* __restrict__ V,  unsigned short* __restrict__ xb16)
{
    __shared__ float Wl[128 * WSTR];
    __shared__ float xl[16 * XSTR];
    const int blk = blockIdx.x, tid = threadIdx.x;
    const int R0 = blk * 16;

    // stage W (4096 float4)
    for (int f = tid; f < 4096; f += 256) {
        int row = f >> 5, c4 = f & 31;
        float4 v = *(const float4*)(W + row * 128 + c4 * 4);
        *(float4*)(Wl + row * WSTR + c4 * 4) = v;
    }
    // stage x tile (256 float4)
    {
        int r = tid >> 4, c4 = tid & 15;
        float4 v = *(const float4*)(x + (size_t)(R0 + r) * ND + c4 * 4);
        *(float4*)(xl + r * XSTR + c4 * 4) = v;
    }
    __syncthreads();

    // bf16 copy: thread -> row tid>>4, cols (tid&15)*4 .. +3
    {
        int r = tid >> 4, c = (tid & 15) * 4;
        float4 v = *(const float4*)(xl + r * XSTR + c);
        ushort4 hb;
        hb.x = f2bf(v.x); hb.y = f2bf(v.y); hb.z = f2bf(v.z); hb.w = f2bf(v.w);
        *(ushort4*)(xb16 + (size_t)(R0 + r) * ND + c) = hb;
    }
    // sq with fp64 accumulation (threads 0..127, 8 lanes per row)
    if (tid < 128) {
        int r = tid >> 3, seg = tid & 7;
        float4 a = *(const float4*)(xl + r * XSTR + seg * 8);
        float4 b = *(const float4*)(xl + r * XSTR + seg * 8 + 4);
        double s = (double)a.x * a.x + (double)a.y * a.y +
                   (double)a.z * a.z + (double)a.w * a.w +
                   (double)b.x * b.x + (double)b.y * b.y +
                   (double)b.z * b.z + (double)b.w * b.w;
        s += __shfl_xor(s, 1, 64);
        s += __shfl_xor(s, 2, 64);
        s += __shfl_xor(s, 4, 64);
        if (seg == 0) sq[R0 + r] = (float)s;
    }

    // U/V: thread -> row r = tid>>4, out channels o = (tid&15) + 16m
    {
        const int r = tid >> 4, g = tid & 15;
        float accP[8], accV[8];
#pragma unroll
        for (int m = 0; m < 8; ++m) { accP[m] = 0.f; accV[m] = 0.f; }
#pragma unroll
        for (int k4 = 0; k4 < 16; ++k4) {
            float4 xv = *(const float4*)(xl + r * XSTR + k4 * 4);
#pragma unroll
            for (int m = 0; m < 8; ++m) {
                const float* wp = Wl + (g + 16 * m) * WSTR + k4 * 4;
                float4 w1 = *(const float4*)(wp);
                float4 w2 = *(const float4*)(wp + 64);
                accP[m] = fmaf(xv.x, w1.x, accP[m]); accP[m] = fmaf(xv.y, w1.y, accP[m]);
                accP[m] = fmaf(xv.z, w1.z, accP[m]); accP[m] = fmaf(xv.w, w1.w, accP[m]);
                accV[m] = fmaf(xv.x, w2.x, accV[m]); accV[m] = fmaf(xv.y, w2.y, accV[m]);
                accV[m] = fmaf(xv.z, w2.z, accV[m]); accV[m] = fmaf(xv.w, w2.w, accV[m]);
            }
        }
        const size_t gr = (size_t)(R0 + r);
#pragma unroll
        for (int m = 0; m < 8; ++m) {
            int o = g + 16 * m;
            U[gr * NOUT + o] = accP[m] - accV[m] + bias[o];
            V[gr * NOUT + o] = accV[m];
        }
    }
}

// ---------------------------------------------------------------------------
// knn + aggregate. grid 4096 x 256 (4 waves), RT=8 rows/block, 4 blocks/CU.
// Block swizzle: XCD x owns batches {2x, 2x+1} (L2 locality for refine/V).
// Phase 1: bf16 MFMA Gram (N-fragment rows 8..15 clamped/wasted)
//          -> fp16 d2 tile in LDS (33 KB).
// Phase 2: per wave 2 rows: radix-select tau (+1.0 abs widen), ballot-compact
//          indices, fp64-exact refine, sort64_u64 -> top-16 set ->
//          V-max + U + relu.
// ---------------------------------------------------------------------------
__global__ void __launch_bounds__(256, 4)
knn_k(const float* __restrict__ x,             // [32768][64] fp32 (refine)
      const unsigned short* __restrict__ xb16, // [32768][64] bf16
      const float* __restrict__ sq,
      const float* __restrict__ U,
      const float* __restrict__ V,
      float* __restrict__ out)
{
    extern __shared__ __align__(16) unsigned char smem[];
    unsigned short* d2h = (unsigned short*)smem;   // [RT][HSTR] halves
    __shared__ unsigned short cbuf[4][128];

    // XCD-aware decode: q%8 = XCD; each XCD gets 2 full batches
    const int q   = blockIdx.x;
    const int xcd = q & 7;
    const int k_  = q >> 3;               // 0..511
    const int bb  = xcd * 2 + (k_ >> 8);  // batch
    const int rt  = k_ & 255;             // row tile within batch
    const int R0l = rt * RT;
    const int R0g = bb * NP + R0l;
    const int tid = threadIdx.x;
    const int w   = tid >> 6;
    const int l   = tid & 63;
    const int l15 = l & 15, lg = l >> 4, kc = lg * 8;

    // N-operand fragments: block rows (clamp l15 >= RT; their output is discarded)
    const int rcl = (l15 < RT) ? l15 : (RT - 1);
    const unsigned short* nr = xb16 + (size_t)(R0g + rcl) * ND + kc;
    bf16x8 n0 = *(const bf16x8*)(nr);
    bf16x8 n1 = *(const bf16x8*)(nr + 32);
    const float sqrow = sq[R0g + rcl];

    const unsigned short* xbb = xb16 + (size_t)bb * NP * ND;
    const float* sqb = sq + bb * NP;

    // ---- Phase 1: MFMA Gram -> fp16 d2 in LDS ----
#pragma unroll 2
    for (int t = 0; t < 32; ++t) {
        const int cb = (w * 32 + t) * 16;
        const unsigned short* ar = xbb + (size_t)(cb + l15) * ND + kc;
        bf16x8 a0 = *(const bf16x8*)(ar);
        bf16x8 a1 = *(const bf16x8*)(ar + 32);
        f32x4 acc = {0.f, 0.f, 0.f, 0.f};
        acc = __builtin_amdgcn_mfma_f32_16x16x32_bf16(a0, n0, acc, 0, 0, 0);
        acc = __builtin_amdgcn_mfma_f32_16x16x32_bf16(a1, n1, acc, 0, 0, 0);
        // D[batch col][block row]: lane holds block row = l15, cols jb4..jb4+3
        const int jb4 = cb + lg * 4;
        float4 sq4 = *(const float4*)(sqb + jb4);
        unsigned short hh[4];
#pragma unroll
        for (int i = 0; i < 4; ++i) {
            float sqc = (i == 0) ? sq4.x : (i == 1) ? sq4.y : (i == 2) ? sq4.z : sq4.w;
            float d2 = fmaxf(fmaf(-2.f, acc[i], sqrow + sqc), 0.f);
            unsigned short h = __builtin_bit_cast(unsigned short, (_Float16)d2);
            if (R0l + l15 == jb4 + i) h = 0x7C00;   // self -> +inf
            hh[i] = h;
        }
        if (l15 < RT) {
            ushort4 hv; hv.x = hh[0]; hv.y = hh[1]; hv.z = hh[2]; hv.w = hh[3];
            *(ushort4*)(d2h + (size_t)l15 * HSTR + jb4) = hv;
        }
    }
    __syncthreads();

    // ---- Phase 2: per-wave 2 rows: selection + refine + aggregation ----
    const int gcbase = bb * NP;
#pragma unroll 1
    for (int rr = 0; rr < 2; ++rr) {
        const int r  = w * 2 + rr;
        const int gr = R0g + r;
        const unsigned short* rowp = d2h + (size_t)r * HSTR;

        // load 32 fp16 values; value slot (s,i) <-> col j = 256*s + 4*l + i
        unsigned int h[32];
#pragma unroll
        for (int s = 0; s < 8; ++s) {
            ushort4 hv = *(const ushort4*)(rowp + (s * 64 + l) * 4);
            h[s*4+0] = hv.x; h[s*4+1] = hv.y; h[s*4+2] = hv.z; h[s*4+3] = hv.w;
        }
        unsigned int mn = h[0];
#pragma unroll
        for (int i = 1; i < 32; ++i) mn = (h[i] < mn) ? h[i] : mn;

        // radix-select: t = 16th smallest of the 64 lane-minima (fp16 bits)
        unsigned int t = 0;
#pragma unroll
        for (int b = 15; b >= 0; --b) {
            unsigned int cand = t | (1u << b);
            int c = __popcll(__ballot(mn < cand));
            if (c < 16) t = cand;
        }
        // widen by +1.0 ABSOLUTE (covers bf16 Gram noise, 11 sigma) + 1 ulp
        float tf = (float)__builtin_bit_cast(_Float16, (unsigned short)t) + 1.0f;
        unsigned int tauh =
            (unsigned int)__builtin_bit_cast(unsigned short, (_Float16)tf) + 1u;

        // compact survivor indices
        cbuf[w][l]      = 0xFFFF;
        cbuf[w][64 + l] = 0xFFFF;
        int base = 0;
#pragma unroll
        for (int s = 0; s < 8; ++s) {
#pragma unroll
            for (int i = 0; i < 4; ++i) {
                bool pred = (h[s*4+i] <= tauh);
                unsigned long long m = __ballot(pred);
                int pos = base + lanes_below(m);
                if (pred && pos < 128)
                    cbuf[w][pos] = (unsigned short)(256 * s + 4 * l + i);
                base += __popcll(m);
            }
        }
        asm volatile("s_waitcnt lgkmcnt(0)" ::: "memory");
        __builtin_amdgcn_sched_barrier(0);

        int jc0 = cbuf[w][l];
        unsigned long long rk0 = refine_key(x, gr, gcbase, jc0);
        if (base > 64) {                          // rare, wave-uniform
            int jc1 = cbuf[w][64 + l];
            unsigned long long rk1 = refine_key(x, gr, gcbase, jc1);
            bitonic_sort128_u64(rk0, rk1, l);
        } else {
            rk0 = bitonic_sort64_u64(rk0, l);
        }
        // lanes 0..15 hold exact top-16 (ties -> ascending index, matches top_k)
        int nbr = (int)(rk0 & 2047u);

        const float* Vb = V + (size_t)bb * NP * NOUT;
        float2 vv[16];
#pragma unroll
        for (int n = 0; n < NK; ++n) {
            int jn = __shfl(nbr, n, 64);
            vv[n] = *(const float2*)(Vb + (size_t)jn * NOUT + (l << 1));
        }
        float mv0 = vv[0].x, mv1 = vv[0].y;
#pragma unroll
        for (int n = 1; n < NK; ++n) {
            mv0 = fmaxf(mv0, vv[n].x);
            mv1 = fmaxf(mv1, vv[n].y);
        }
        float2 uu = *(const float2*)(U + (size_t)gr * NOUT + (l << 1));
        float2 ov;
        ov.x = fmaxf(uu.x + mv0, 0.f);
        ov.y = fmaxf(uu.y + mv1, 0.f);
        *(float2*)(out + (size_t)gr * NOUT + (l << 1)) = ov;
    }
}

extern "C" void kernel_launch(void* const* d_in, const int* in_sizes, int n_in,
                              void* d_out, int out_size, void* d_ws, size_t ws_size,
                              hipStream_t stream) {
    const float* x    = (const float*)d_in[0];   // fp32 [32768][64]
    // d_in[1] = pos (unused), d_in[2] = batch (unused; uniform sorted segments)
    const float* W    = (const float*)d_in[3];   // fp32 [128][128]
    const float* bias = (const float*)d_in[4];   // fp32 [128]
    float* out = (float*)d_out;                  // fp32 [32768][128]

    float* sq = (float*)d_ws;                               // 32768 f32
    float* U  = sq + NBAT * NP;                             // 4.19M f32
    float* V  = U  + (size_t)NBAT * NP * NOUT;              // 4.19M f32
    unsigned short* xb16 = (unsigned short*)(V + (size_t)NBAT * NP * NOUT);

    prep_k<<<2048, 256, 0, stream>>>(x, W, bias, sq, U, V, xb16);

    const int lds_bytes = RT * HSTR * 2;                    // 32,832 B
    (void)hipFuncSetAttribute((const void*)knn_k,
                        hipFuncAttributeMaxDynamicSharedMemorySize, lds_bytes);
    const int nblk2 = NBAT * (NP / RT);                     // 4096
    knn_k<<<nblk2, 256, lds_bytes, stream>>>(x, xb16, sq, U, V, out);
}

// Round 8
// 190.864 us; speedup vs baseline: 1.2785x; 1.2785x over previous
//
#include <hip/hip_runtime.h>

typedef __bf16 bf16x8 __attribute__((ext_vector_type(8)));
typedef float  f32x4  __attribute__((ext_vector_type(4)));

#define NBAT 16
#define NP   2048
#define ND   64
#define NOUT 128
#define NK   16
#define RT   16            // rows per knn block
#define HSTR 2052          // d2 LDS row stride in halves (4104 B, 8B-aligned)
#define WSTR 132           // W LDS stride (floats)
#define XSTR 68            // x tile LDS stride (floats)

static __device__ __forceinline__ unsigned short f2bf(float f) {
    unsigned u = __float_as_uint(f);
    u += 0x7FFF + ((u >> 16) & 1);      // RNE
    return (unsigned short)(u >> 16);
}
static __device__ __forceinline__ int lanes_below(unsigned long long m) {
    return (int)__builtin_amdgcn_mbcnt_hi((unsigned)(m >> 32),
             __builtin_amdgcn_mbcnt_lo((unsigned)m, 0u));
}
static __device__ __forceinline__ unsigned int umin32(unsigned int a, unsigned int b){ return a < b ? a : b; }
static __device__ __forceinline__ unsigned int umax32(unsigned int a, unsigned int b){ return a < b ? b : a; }
static __device__ __forceinline__ unsigned long long umin64(unsigned long long a, unsigned long long b){ return a < b ? a : b; }
static __device__ __forceinline__ unsigned long long umax64(unsigned long long a, unsigned long long b){ return a < b ? b : a; }

// ascending bitonic sort of 64 u32 keys (one per lane)
static __device__ __forceinline__ unsigned int bitonic_sort64_u32(unsigned int v, int lane) {
#pragma unroll
    for (int k = 2; k <= 64; k <<= 1) {
#pragma unroll
        for (int j = k >> 1; j >= 1; j >>= 1) {
            unsigned int o = __shfl_xor(v, j, 64);
            bool up    = ((lane & k) == 0);
            bool lower = ((lane & j) == 0);
            v = (up == lower) ? umin32(v, o) : umax32(v, o);
        }
    }
    return v;
}

// ascending bitonic sort of 64 u64 keys (one per lane)
static __device__ __forceinline__ unsigned long long bitonic_sort64_u64(unsigned long long v, int lane) {
#pragma unroll
    for (int k = 2; k <= 64; k <<= 1) {
#pragma unroll
        for (int j = k >> 1; j >= 1; j >>= 1) {
            unsigned long long o = __shfl_xor(v, j, 64);
            bool up    = ((lane & k) == 0);
            bool lower = ((lane & j) == 0);
            v = (up == lower) ? umin64(v, o) : umax64(v, o);
        }
    }
    return v;
}

// ascending bitonic sort of 128 u64 keys, element e = slot*64 + lane (rare path)
static __device__ __forceinline__ void bitonic_sort128_u64(unsigned long long &k0,
                                                           unsigned long long &k1, int lane) {
#pragma unroll
    for (int k = 2; k <= 64; k <<= 1) {
#pragma unroll
        for (int j = k >> 1; j >= 1; j >>= 1) {
            bool lower = ((lane & j) == 0);
            bool up0 = (k == 64) ? true  : ((lane & k) == 0);
            bool up1 = (k == 64) ? false : ((lane & k) == 0);
            unsigned long long o0 = __shfl_xor(k0, j, 64);
            k0 = (up0 == lower) ? umin64(k0, o0) : umax64(k0, o0);
            unsigned long long o1 = __shfl_xor(k1, j, 64);
            k1 = (up1 == lower) ? umin64(k1, o1) : umax64(k1, o1);
        }
    }
    { unsigned long long mn = umin64(k0, k1), mx = umax64(k0, k1); k0 = mn; k1 = mx; }
#pragma unroll
    for (int j = 32; j >= 1; j >>= 1) {
        bool lower = ((lane & j) == 0);
        unsigned long long o0 = __shfl_xor(k0, j, 64);
        k0 = lower ? umin64(k0, o0) : umax64(k0, o0);
        unsigned long long o1 = __shfl_xor(k1, j, 64);
        k1 = lower ? umin64(k1, o1) : umax64(k1, o1);
    }
}

// fp64-exact squared distance -> sortable key (fp32 bits << 11 | idx)
static __device__ __forceinline__ unsigned long long
refine_key(const float* __restrict__ x, int gr, int gcbase, int jc) {
    if (jc == 0xFFFF) return ~0ull;
    const float* xr = x + (size_t)gr * ND;
    const float* xc = x + (size_t)(gcbase + jc) * ND;
    double s0 = 0.0, s1 = 0.0;
#pragma unroll
    for (int k8 = 0; k8 < 8; ++k8) {
        float4 a = *(const float4*)(xr + k8 * 8);
        float4 b = *(const float4*)(xc + k8 * 8);
        float4 a2 = *(const float4*)(xr + k8 * 8 + 4);
        float4 b2 = *(const float4*)(xc + k8 * 8 + 4);
        double e0 = (double)a.x - (double)b.x;
        double e1 = (double)a.y - (double)b.y;
        double e2 = (double)a.z - (double)b.z;
        double e3 = (double)a.w - (double)b.w;
        s0 = fma(e0, e0, s0); s0 = fma(e1, e1, s0);
        s0 = fma(e2, e2, s0); s0 = fma(e3, e3, s0);
        double f0 = (double)a2.x - (double)b2.x;
        double f1 = (double)a2.y - (double)b2.y;
        double f2 = (double)a2.z - (double)b2.z;
        double f3 = (double)a2.w - (double)b2.w;
        s1 = fma(f0, f0, s1); s1 = fma(f1, f1, s1);
        s1 = fma(f2, f2, s1); s1 = fma(f3, f3, s1);
    }
    float d = (float)(s0 + s1);
    return (((unsigned long long)__float_as_uint(d)) << 11) | (unsigned)jc;
}

// ---------------------------------------------------------------------------
// prep: sq (fp64-acc), xb16 (bf16 copy of x), U=(W1-W2)x+b, V=W2x  (fp32)
// grid 2048 x 256 (16 rows/block)
// ---------------------------------------------------------------------------
__global__ void __launch_bounds__(256, 1)
prep_k(const float* __restrict__ x,     // [32768][64]
       const float* __restrict__ W,     // [128][128]  (cols 0..63 = W1, 64..127 = W2)
       const float* __restrict__ bias,  // [128]
       float* __restrict__ sq, float* __restrict__ U,
       float* __restrict__ V,  unsigned short* __restrict__ xb16)
{
    __shared__ float Wl[128 * WSTR];
    __shared__ float xl[16 * XSTR];
    const int blk = blockIdx.x, tid = threadIdx.x;
    const int R0 = blk * 16;

    // stage W (4096 float4)
    for (int f = tid; f < 4096; f += 256) {
        int row = f >> 5, c4 = f & 31;
        float4 v = *(const float4*)(W + row * 128 + c4 * 4);
        *(float4*)(Wl + row * WSTR + c4 * 4) = v;
    }
    // stage x tile (256 float4)
    {
        int r = tid >> 4, c4 = tid & 15;
        float4 v = *(const float4*)(x + (size_t)(R0 + r) * ND + c4 * 4);
        *(float4*)(xl + r * XSTR + c4 * 4) = v;
    }
    __syncthreads();

    // bf16 copy: thread -> row tid>>4, cols (tid&15)*4 .. +3
    {
        int r = tid >> 4, c = (tid & 15) * 4;
        float4 v = *(const float4*)(xl + r * XSTR + c);
        ushort4 hb;
        hb.x = f2bf(v.x); hb.y = f2bf(v.y); hb.z = f2bf(v.z); hb.w = f2bf(v.w);
        *(ushort4*)(xb16 + (size_t)(R0 + r) * ND + c) = hb;
    }
    // sq with fp64 accumulation (threads 0..127, 8 lanes per row)
    if (tid < 128) {
        int r = tid >> 3, seg = tid & 7;
        float4 a = *(const float4*)(xl + r * XSTR + seg * 8);
        float4 b = *(const float4*)(xl + r * XSTR + seg * 8 + 4);
        double s = (double)a.x * a.x + (double)a.y * a.y +
                   (double)a.z * a.z + (double)a.w * a.w +
                   (double)b.x * b.x + (double)b.y * b.y +
                   (double)b.z * b.z + (double)b.w * b.w;
        s += __shfl_xor(s, 1, 64);
        s += __shfl_xor(s, 2, 64);
        s += __shfl_xor(s, 4, 64);
        if (seg == 0) sq[R0 + r] = (float)s;
    }

    // U/V: thread -> row r = tid>>4, out channels o = (tid&15) + 16m
    {
        const int r = tid >> 4, g = tid & 15;
        float accP[8], accV[8];
#pragma unroll
        for (int m = 0; m < 8; ++m) { accP[m] = 0.f; accV[m] = 0.f; }
#pragma unroll
        for (int k4 = 0; k4 < 16; ++k4) {
            float4 xv = *(const float4*)(xl + r * XSTR + k4 * 4);
#pragma unroll
            for (int m = 0; m < 8; ++m) {
                const float* wp = Wl + (g + 16 * m) * WSTR + k4 * 4;
                float4 w1 = *(const float4*)(wp);
                float4 w2 = *(const float4*)(wp + 64);
                accP[m] = fmaf(xv.x, w1.x, accP[m]); accP[m] = fmaf(xv.y, w1.y, accP[m]);
                accP[m] = fmaf(xv.z, w1.z, accP[m]); accP[m] = fmaf(xv.w, w1.w, accP[m]);
                accV[m] = fmaf(xv.x, w2.x, accV[m]); accV[m] = fmaf(xv.y, w2.y, accV[m]);
                accV[m] = fmaf(xv.z, w2.z, accV[m]); accV[m] = fmaf(xv.w, w2.w, accV[m]);
            }
        }
        const size_t gr = (size_t)(R0 + r);
#pragma unroll
        for (int m = 0; m < 8; ++m) {
            int o = g + 16 * m;
            U[gr * NOUT + o] = accP[m] - accV[m] + bias[o];
            V[gr * NOUT + o] = accV[m];
        }
    }
}

// ---------------------------------------------------------------------------
// knn + aggregate. grid 2048 x 512 (8 waves), RT=16, 2 blocks/CU (~16 waves/CU).
// Block swizzle: XCD x owns batches {2x, 2x+1}.
// Phase 1: bf16 MFMA Gram -> fp16 d2 tile (66 KB LDS); each wave 16 col-tiles.
// Phase 2: each wave 2 rows: tau via bitonic sort64_u32 (+1.0 abs widen),
//          scan-based compaction (<=4 survivors/lane fast path), fp64-exact
//          refine, sort64_u64 -> top-16 set -> V-max + U + relu.
// ---------------------------------------------------------------------------
__global__ void __launch_bounds__(512, 2)
knn_k(const float* __restrict__ x,             // [32768][64] fp32 (refine)
      const unsigned short* __restrict__ xb16, // [32768][64] bf16
      const float* __restrict__ sq,
      const float* __restrict__ U,
      const float* __restrict__ V,
      float* __restrict__ out)
{
    extern __shared__ __align__(16) unsigned char smem[];
    unsigned short* d2h = (unsigned short*)smem;   // [RT][HSTR] halves
    __shared__ unsigned short cbuf[8][128];

    // XCD-aware decode: q%8 = XCD; each XCD gets 2 full batches
    const int q   = blockIdx.x;
    const int xcd = q & 7;
    const int k_  = q >> 3;               // 0..255
    const int bb  = xcd * 2 + (k_ >> 7);  // batch
    const int rt  = k_ & 127;             // row tile within batch
    const int R0l = rt * RT;
    const int R0g = bb * NP + R0l;
    const int tid = threadIdx.x;
    const int w   = tid >> 6;             // 0..7
    const int l   = tid & 63;
    const int l15 = l & 15, lg = l >> 4, kc = lg * 8;

    // N-operand fragments: the 16 block rows
    const unsigned short* nr = xb16 + (size_t)(R0g + l15) * ND + kc;
    bf16x8 n0 = *(const bf16x8*)(nr);
    bf16x8 n1 = *(const bf16x8*)(nr + 32);
    const float sqrow = sq[R0g + l15];

    const unsigned short* xbb = xb16 + (size_t)bb * NP * ND;
    const float* sqb = sq + bb * NP;

    // ---- Phase 1: MFMA Gram -> fp16 d2 in LDS (16 col-tiles per wave) ----
#pragma unroll 2
    for (int t = 0; t < 16; ++t) {
        const int cb = (w * 16 + t) * 16;
        const unsigned short* ar = xbb + (size_t)(cb + l15) * ND + kc;
        bf16x8 a0 = *(const bf16x8*)(ar);
        bf16x8 a1 = *(const bf16x8*)(ar + 32);
        f32x4 acc = {0.f, 0.f, 0.f, 0.f};
        acc = __builtin_amdgcn_mfma_f32_16x16x32_bf16(a0, n0, acc, 0, 0, 0);
        acc = __builtin_amdgcn_mfma_f32_16x16x32_bf16(a1, n1, acc, 0, 0, 0);
        // D[batch col][block row]: lane holds block row = l15, cols jb4..jb4+3
        const int jb4 = cb + lg * 4;
        float4 sq4 = *(const float4*)(sqb + jb4);
        unsigned short hh[4];
#pragma unroll
        for (int i = 0; i < 4; ++i) {
            float sqc = (i == 0) ? sq4.x : (i == 1) ? sq4.y : (i == 2) ? sq4.z : sq4.w;
            float d2 = fmaxf(fmaf(-2.f, acc[i], sqrow + sqc), 0.f);
            unsigned short h = __builtin_bit_cast(unsigned short, (_Float16)d2);
            if (R0l + l15 == jb4 + i) h = 0x7C00;   // self -> +inf
            hh[i] = h;
        }
        ushort4 hv; hv.x = hh[0]; hv.y = hh[1]; hv.z = hh[2]; hv.w = hh[3];
        *(ushort4*)(d2h + (size_t)l15 * HSTR + jb4) = hv;
    }
    __syncthreads();

    // ---- Phase 2: per-wave 2 rows ----
    const int gcbase = bb * NP;
#pragma unroll 1
    for (int rr = 0; rr < 2; ++rr) {
        const int r  = w * 2 + rr;
        const int gr = R0g + r;
        const unsigned short* rowp = d2h + (size_t)r * HSTR;

        // load 32 fp16 values; value slot (s,i) <-> col j = 256*s + 4*l + i
        unsigned int h[32];
#pragma unroll
        for (int s = 0; s < 8; ++s) {
            ushort4 hv = *(const ushort4*)(rowp + (s * 64 + l) * 4);
            h[s*4+0] = hv.x; h[s*4+1] = hv.y; h[s*4+2] = hv.z; h[s*4+3] = hv.w;
        }
        unsigned int mnh = h[0];
#pragma unroll
        for (int i = 1; i < 32; ++i) mnh = (h[i] < mnh) ? h[i] : mnh;

        // tau = 16th smallest of the 64 lane-minima via bitonic sort
        unsigned int srt = bitonic_sort64_u32(mnh, l);
        unsigned int tau16 = __shfl(srt, 15, 64);
        // widen by +1.0 ABSOLUTE (covers bf16 Gram noise, 11 sigma) + 1 ulp
        float tf = (float)__builtin_bit_cast(_Float16, (unsigned short)tau16) + 1.0f;
        unsigned int tauh =
            (unsigned int)__builtin_bit_cast(unsigned short, (_Float16)tf) + 1u;

        // per-lane survivor pack (slot ids, 5 bits each, up to 4)
        unsigned int packed = 0; int cnt = 0;
#pragma unroll
        for (int i = 0; i < 32; ++i) {
            if (h[i] <= tauh) {
                if (cnt < 4) packed |= (unsigned)i << (5 * cnt);
                ++cnt;
            }
        }
        bool ovf = (__ballot(cnt > 4) != 0ull);   // wave-uniform

        cbuf[w][l]      = 0xFFFF;
        cbuf[w][64 + l] = 0xFFFF;
        int total;
        if (!ovf) {
            // exclusive scan of cnt (6 shfl_up steps)
            int inc = cnt;
#pragma unroll
            for (int off = 1; off < 64; off <<= 1) {
                int nv = __shfl_up(inc, off, 64);
                if (l >= off) inc += nv;
            }
            int excl = inc - cnt;
            total = __shfl(inc, 63, 64);
#pragma unroll
            for (int kk = 0; kk < 4; ++kk) {
                if (kk < cnt && excl + kk < 128) {
                    int slot = (packed >> (5 * kk)) & 31;
                    cbuf[w][excl + kk] =
                        (unsigned short)(256 * (slot >> 2) + 4 * l + (slot & 3));
                }
            }
        } else {
            // rare slow path: serial ballot compaction
            int base = 0;
#pragma unroll 1
            for (int i = 0; i < 32; ++i) {
                bool pred = (h[i] <= tauh);
                unsigned long long m = __ballot(pred);
                int pos = base + lanes_below(m);
                if (pred && pos < 128)
                    cbuf[w][pos] = (unsigned short)(256 * (i >> 2) + 4 * l + (i & 3));
                base += __popcll(m);
            }
            total = base;
        }
        asm volatile("s_waitcnt lgkmcnt(0)" ::: "memory");
        __builtin_amdgcn_sched_barrier(0);

        int jc0 = cbuf[w][l];
        unsigned long long rk0 = refine_key(x, gr, gcbase, jc0);
        if (total > 64) {                          // rare, wave-uniform
            int jc1 = cbuf[w][64 + l];
            unsigned long long rk1 = refine_key(x, gr, gcbase, jc1);
            bitonic_sort128_u64(rk0, rk1, l);
        } else {
            rk0 = bitonic_sort64_u64(rk0, l);
        }
        // lanes 0..15 hold exact top-16 (ties -> ascending index, matches top_k)
        int nbr = (int)(rk0 & 2047u);

        const float* Vb = V + (size_t)bb * NP * NOUT;
        float2 vv[16];
#pragma unroll
        for (int n = 0; n < NK; ++n) {
            int jn = __shfl(nbr, n, 64);
            vv[n] = *(const float2*)(Vb + (size_t)jn * NOUT + (l << 1));
        }
        float mv0 = vv[0].x, mv1 = vv[0].y;
#pragma unroll
        for (int n = 1; n < NK; ++n) {
            mv0 = fmaxf(mv0, vv[n].x);
            mv1 = fmaxf(mv1, vv[n].y);
        }
        float2 uu = *(const float2*)(U + (size_t)gr * NOUT + (l << 1));
        float2 ov;
        ov.x = fmaxf(uu.x + mv0, 0.f);
        ov.y = fmaxf(uu.y + mv1, 0.f);
        *(float2*)(out + (size_t)gr * NOUT + (l << 1)) = ov;
    }
}

extern "C" void kernel_launch(void* const* d_in, const int* in_sizes, int n_in,
                              void* d_out, int out_size, void* d_ws, size_t ws_size,
                              hipStream_t stream) {
    const float* x    = (const float*)d_in[0];   // fp32 [32768][64]
    // d_in[1] = pos (unused), d_in[2] = batch (unused; uniform sorted segments)
    const float* W    = (const float*)d_in[3];   // fp32 [128][128]
    const float* bias = (const float*)d_in[4];   // fp32 [128]
    float* out = (float*)d_out;                  // fp32 [32768][128]

    float* sq = (float*)d_ws;                               // 32768 f32
    float* U  = sq + NBAT * NP;                             // 4.19M f32
    float* V  = U  + (size_t)NBAT * NP * NOUT;              // 4.19M f32
    unsigned short* xb16 = (unsigned short*)(V + (size_t)NBAT * NP * NOUT);

    prep_k<<<2048, 256, 0, stream>>>(x, W, bias, sq, U, V, xb16);

    const int lds_bytes = RT * HSTR * 2;                    // 65,664 B
    (void)hipFuncSetAttribute((const void*)knn_k,
                        hipFuncAttributeMaxDynamicSharedMemorySize, lds_bytes);
    knn_k<<<2048, 512, lds_bytes, stream>>>(x, xb16, sq, U, V, out);
}